// Round 1
// baseline (422.727 us; speedup 1.0000x reference)
//
#include <hip/hip_runtime.h>
#include <hip/hip_bf16.h>
#include <math.h>

#define NTOT 8192
#define HB   4096
#define DIM  256
#define RANK_N (4096*19)
#define INV_T 14.285714285714286f
#define SHIFT 16.0f

typedef __attribute__((ext_vector_type(8))) short bf16x8_t;
typedef __attribute__((ext_vector_type(4))) float f32x4_t;

__device__ __forceinline__ unsigned short f2bf(float f) {
  union { float fv; unsigned int u; } v; v.fv = f;
  unsigned int u = v.u;
  unsigned int r = u + 0x7FFFu + ((u >> 16) & 1u);
  return (unsigned short)(r >> 16);
}

__device__ __forceinline__ const float* zrow(const float* za, const float* zb, int g) {
  return g < HB ? za + (size_t)g * DIM : zb + (size_t)(g - HB) * DIM;
}
__device__ __forceinline__ int piece_of(const int* pa, const int* pb, int g) {
  return g < HB ? pa[g] : pb[g - HB];
}

// ---------------- K1: inv_norm + piece histogram ----------------
__global__ void k_norm(const float* __restrict__ za, const float* __restrict__ zb,
                       const int* __restrict__ pa, const int* __restrict__ pb,
                       float* __restrict__ inv_norm, int* __restrict__ hist) {
  int lane = threadIdx.x & 63;
  int w = threadIdx.x >> 6;
  int row = blockIdx.x * 4 + w;
  const float* src = zrow(za, zb, row);
  float4 v = *reinterpret_cast<const float4*>(src + lane * 4);
  float ss = v.x * v.x + v.y * v.y + v.z * v.z + v.w * v.w;
  for (int o = 32; o; o >>= 1) ss += __shfl_xor(ss, o, 64);
  if (lane == 0) {
    inv_norm[row] = 1.0f / fmaxf(sqrtf(ss), 1e-8f);
    atomicAdd(&hist[piece_of(pa, pb, row)], 1);
  }
}

// ---------------- K2: ranking BCE ----------------
__global__ void k_rank(const float* __restrict__ logits, const float* __restrict__ la,
                       const float* __restrict__ lb, float* __restrict__ accf) {
  int idx = blockIdx.x * 256 + threadIdx.x;
  float lsum = 0.f, lcnt = 0.f;
  for (int e = idx; e < RANK_N; e += gridDim.x * 256) {
    float diff = la[e] - lb[e];
    if (fabsf(diff) >= 0.05f) {
      float x = logits[e];
      float tgt = diff > 0.f ? 0.95f : 0.05f;
      float bce = fmaxf(x, 0.f) - x * tgt + log1pf(__expf(-fabsf(x)));
      lsum += bce;
      lcnt += 1.f;
    }
  }
  for (int o = 32; o; o >>= 1) { lsum += __shfl_xor(lsum, o, 64); lcnt += __shfl_xor(lcnt, o, 64); }
  __shared__ float sred[8];
  int w = threadIdx.x >> 6, lane = threadIdx.x & 63;
  if (lane == 0) { sred[w * 2] = lsum; sred[w * 2 + 1] = lcnt; }
  __syncthreads();
  if (threadIdx.x == 0) {
    float S = 0.f, C = 0.f;
    for (int i = 0; i < 4; ++i) { S += sred[i * 2]; C += sred[i * 2 + 1]; }
    atomicAdd(&accf[0], S);
    atomicAdd(&accf[1], C);
  }
}

// ---------------- K3: Gram matrix + masked sum of exp(sim-16) ----------------
// grid 512: it = bid>>3 (128-row i-tile), chunk = bid&7 (1024-col j-range)
__global__ __launch_bounds__(256, 2)
void k_gram(const float* __restrict__ za, const float* __restrict__ zb,
            const int* __restrict__ pa, const int* __restrict__ pb,
            const float* __restrict__ inv_norm, float* __restrict__ neg_s) {
  __shared__ unsigned short Bs[64 * 264];
  const int t = threadIdx.x;
  const int lane = t & 63;
  const int w = t >> 6;          // wave 0..3, owns rows [w*32, w*32+32)
  const int l15 = lane & 15;
  const int lg = lane >> 4;      // 0..3
  const int it = blockIdx.x >> 3;
  const int chunk = blockIdx.x & 7;
  const int ibase = it * 128;
  const int jbase0 = chunk * 1024;

  // A fragments in registers: 2 m-tiles x 8 k-steps
  bf16x8_t afrag[2][8];
  for (int mt = 0; mt < 2; ++mt) {
    int garow = ibase + w * 32 + mt * 16 + l15;
    const float* asrc = zrow(za, zb, garow);
    float ai = inv_norm[garow];
    for (int ks = 0; ks < 8; ++ks) {
      int k0 = lg * 8 + ks * 32;
      float4 u0 = *reinterpret_cast<const float4*>(asrc + k0);
      float4 u1 = *reinterpret_cast<const float4*>(asrc + k0 + 4);
      union { bf16x8_t b; unsigned short us[8]; } tmp;
      tmp.us[0] = f2bf(u0.x * ai); tmp.us[1] = f2bf(u0.y * ai);
      tmp.us[2] = f2bf(u0.z * ai); tmp.us[3] = f2bf(u0.w * ai);
      tmp.us[4] = f2bf(u1.x * ai); tmp.us[5] = f2bf(u1.y * ai);
      tmp.us[6] = f2bf(u1.z * ai); tmp.us[7] = f2bf(u1.w * ai);
      afrag[mt][ks] = tmp.b;
    }
  }

  int prow[8];
  for (int mt = 0; mt < 2; ++mt)
    for (int r = 0; r < 4; ++r)
      prow[mt * 4 + r] = piece_of(pa, pb, ibase + w * 32 + mt * 16 + lg * 4 + r);

  float s[8] = {0.f, 0.f, 0.f, 0.f, 0.f, 0.f, 0.f, 0.f};

  for (int jt = 0; jt < 16; ++jt) {
    int jb = jbase0 + jt * 64;
    __syncthreads();
    // stage 64x256 f32 -> normalized bf16 LDS tile (pad to 264)
    for (int i = 0; i < 16; ++i) {
      int f = t + i * 256;
      int r = f >> 6;
      int c4 = f & 63;
      int g = jb + r;
      const float* src = zrow(za, zb, g);
      float4 v = *reinterpret_cast<const float4*>(src + c4 * 4);
      float sc = inv_norm[g];
      ushort4 o;
      o.x = f2bf(v.x * sc); o.y = f2bf(v.y * sc);
      o.z = f2bf(v.z * sc); o.w = f2bf(v.w * sc);
      *reinterpret_cast<ushort4*>(&Bs[r * 264 + c4 * 4]) = o;
    }
    __syncthreads();
    for (int ct = 0; ct < 4; ++ct) {
      int jj = jb + ct * 16 + l15;
      int pc = piece_of(pa, pb, jj);
      int brow = ct * 16 + l15;
      f32x4_t acc0 = {0.f, 0.f, 0.f, 0.f};
      f32x4_t acc1 = {0.f, 0.f, 0.f, 0.f};
      for (int ks = 0; ks < 8; ++ks) {
        bf16x8_t bfrag = *reinterpret_cast<const bf16x8_t*>(&Bs[brow * 264 + lg * 8 + ks * 32]);
        acc0 = __builtin_amdgcn_mfma_f32_16x16x32_bf16(afrag[0][ks], bfrag, acc0, 0, 0, 0);
        acc1 = __builtin_amdgcn_mfma_f32_16x16x32_bf16(afrag[1][ks], bfrag, acc1, 0, 0, 0);
      }
      for (int r = 0; r < 4; ++r) {
        if (pc != prow[r])     s[r]     += __expf(acc0[r] * INV_T - SHIFT);
        if (pc != prow[4 + r]) s[4 + r] += __expf(acc1[r] * INV_T - SHIFT);
      }
    }
  }
  for (int q = 0; q < 8; ++q) {
    float v = s[q];
    v += __shfl_xor(v, 1, 64);
    v += __shfl_xor(v, 2, 64);
    v += __shfl_xor(v, 4, 64);
    v += __shfl_xor(v, 8, 64);
    if (l15 == 0) {
      int mt = q >> 2, r = q & 3;
      atomicAdd(&neg_s[ibase + w * 32 + mt * 16 + lg * 4 + r], v);
    }
  }
}

// ---------------- K4: positive-pair terms ----------------
__global__ void k_pos(const float* __restrict__ za, const float* __restrict__ zb,
                      const int* __restrict__ pa, const int* __restrict__ pb,
                      const float* __restrict__ inv_norm, const float* __restrict__ neg_s,
                      const int* __restrict__ hist,
                      float* __restrict__ accf, int* __restrict__ acci) {
  int lane = threadIdx.x & 63;
  int w = threadIdx.x >> 6;
  int i = blockIdx.x * 4 + w;
  int pi = piece_of(pa, pb, i);
  int cnt = hist[pi];
  int posCnt = cnt - 1;
  int negCnt = NTOT - cnt;
  if (posCnt <= 0 || negCnt <= 0) return;
  const float* zi = zrow(za, zb, i);
  float4 vi = *reinterpret_cast<const float4*>(zi + lane * 4);
  float inv_i = inv_norm[i];
  float nlse = SHIFT + logf(neg_s[i]);
  float lsum = 0.f;
  for (int c = 0; c < NTOT / 64; ++c) {
    int j = c * 64 + lane;
    int pj = piece_of(pa, pb, j);
    unsigned long long m = __ballot(pj == pi && j != i);
    while (m) {
      int b = __ffsll((unsigned long long)m) - 1;
      m &= m - 1;
      int jm = c * 64 + b;
      const float* zj = zrow(za, zb, jm);
      float4 vj = *reinterpret_cast<const float4*>(zj + lane * 4);
      float d = vi.x * vj.x + vi.y * vj.y + vi.z * vj.z + vi.w * vj.w;
      for (int o = 32; o; o >>= 1) d += __shfl_xor(d, o, 64);
      float sim = d * inv_i * inv_norm[jm] * INV_T;
      float x = nlse - sim;
      lsum += fmaxf(x, 0.f) + log1pf(__expf(-fabsf(x)));
    }
  }
  if (lane == 0) {
    atomicAdd(&accf[2], lsum);
    atomicAdd(&acci[3], posCnt);
  }
}

// ---------------- K5: finalize ----------------
__global__ void k_final(const float* __restrict__ accf, const int* __restrict__ acci,
                        float* __restrict__ out) {
  float rs = accf[0], rc = accf[1], ps = accf[2];
  int pc = acci[3];
  float l_rank = rc > 0.f ? rs / rc : 0.f;
  float l_con = pc > 0 ? ps / (float)pc : 0.f;
  out[0] = l_rank + 0.3f * l_con;
  out[1] = l_rank;
  out[2] = l_con;
}

extern "C" void kernel_launch(void* const* d_in, const int* in_sizes, int n_in,
                              void* d_out, int out_size, void* d_ws, size_t ws_size,
                              hipStream_t stream) {
  const float* za     = (const float*)d_in[0];
  const float* zb     = (const float*)d_in[1];
  const float* logits = (const float*)d_in[2];
  const float* la     = (const float*)d_in[3];
  const float* lb     = (const float*)d_in[4];
  const int*   pa     = (const int*)d_in[5];
  const int*   pb     = (const int*)d_in[6];
  float* out = (float*)d_out;

  // ws layout (floats): [0]=rank_sum [1]=rank_cnt [2]=pos_sum [3]=pos_cnt(int)
  // [4 .. 4+8192) neg_s ; then 1024 ints hist ; then 8192 floats inv_norm
  float* wsf = (float*)d_ws;
  int*   wsi = (int*)d_ws;
  float* neg_s    = wsf + 4;
  int*   hist     = wsi + 4 + NTOT;
  float* inv_norm = wsf + 4 + NTOT + 1024;

  hipMemsetAsync(d_ws, 0, (size_t)(4 + NTOT + 1024) * 4, stream);
  k_norm<<<NTOT / 4, 256, 0, stream>>>(za, zb, pa, pb, inv_norm, hist);
  k_rank<<<128, 256, 0, stream>>>(logits, la, lb, wsf);
  k_gram<<<512, 256, 0, stream>>>(za, zb, pa, pb, inv_norm, neg_s);
  k_pos<<<NTOT / 4, 256, 0, stream>>>(za, zb, pa, pb, inv_norm, neg_s, hist, wsf, wsi);
  k_final<<<1, 1, 0, stream>>>(wsf, wsi, out);
}

// Round 3
// 189.636 us; speedup vs baseline: 2.2291x; 2.2291x over previous
//
#include <hip/hip_runtime.h>
#include <hip/hip_bf16.h>
#include <math.h>

#define NTOT 8192
#define HB   4096
#define DIM  256
#define RANK_N (4096*19)
#define INV_T 14.285714285714286f
#define SHIFT 16.0f
#define MAXP  48

typedef __attribute__((ext_vector_type(8))) short bf16x8_t;
typedef __attribute__((ext_vector_type(4))) float f32x4_t;

__device__ __forceinline__ unsigned short f2bf(float f) {
  union { float fv; unsigned int u; } v; v.fv = f;
  unsigned int u = v.u;
  unsigned int r = u + 0x7FFFu + ((u >> 16) & 1u);
  return (unsigned short)(r >> 16);
}

__device__ __forceinline__ const float* zrow(const float* za, const float* zb, int g) {
  return g < HB ? za + (size_t)g * DIM : zb + (size_t)(g - HB) * DIM;
}
__device__ __forceinline__ int piece_of(const int* pa, const int* pb, int g) {
  return g < HB ? pa[g] : pb[g - HB];
}

// ---------------- K1: normalize -> bf16, piece histogram ----------------
__global__ void k_norm(const float* __restrict__ za, const float* __restrict__ zb,
                       const int* __restrict__ pa, const int* __restrict__ pb,
                       unsigned short* __restrict__ zn, int* __restrict__ hist) {
  int lane = threadIdx.x & 63;
  int w = threadIdx.x >> 6;
  int row = blockIdx.x * 4 + w;
  const float* src = zrow(za, zb, row);
  float4 v = *reinterpret_cast<const float4*>(src + lane * 4);
  float ss = v.x * v.x + v.y * v.y + v.z * v.z + v.w * v.w;
  for (int o = 32; o; o >>= 1) ss += __shfl_xor(ss, o, 64);  // butterfly: all lanes
  float inv = 1.0f / fmaxf(sqrtf(ss), 1e-8f);
  ushort4 o;
  o.x = f2bf(v.x * inv); o.y = f2bf(v.y * inv);
  o.z = f2bf(v.z * inv); o.w = f2bf(v.w * inv);
  *reinterpret_cast<ushort4*>(zn + (size_t)row * DIM + lane * 4) = o;
  if (lane == 0) atomicAdd(&hist[piece_of(pa, pb, row)], 1);
}

// ---------------- K2: ranking BCE ----------------
__global__ void k_rank(const float* __restrict__ logits, const float* __restrict__ la,
                       const float* __restrict__ lb, float* __restrict__ accf) {
  int e = blockIdx.x * 256 + threadIdx.x;  // grid covers RANK_N exactly
  float lsum = 0.f, lcnt = 0.f;
  float diff = la[e] - lb[e];
  if (fabsf(diff) >= 0.05f) {
    float x = logits[e];
    float tgt = diff > 0.f ? 0.95f : 0.05f;
    lsum = fmaxf(x, 0.f) - x * tgt + log1pf(__expf(-fabsf(x)));
    lcnt = 1.f;
  }
  for (int o = 32; o; o >>= 1) { lsum += __shfl_xor(lsum, o, 64); lcnt += __shfl_xor(lcnt, o, 64); }
  __shared__ float sred[8];
  int w = threadIdx.x >> 6, lane = threadIdx.x & 63;
  if (lane == 0) { sred[w * 2] = lsum; sred[w * 2 + 1] = lcnt; }
  __syncthreads();
  if (threadIdx.x == 0) {
    float S = 0.f, C = 0.f;
    for (int i = 0; i < 4; ++i) { S += sred[i * 2]; C += sred[i * 2 + 1]; }
    atomicAdd(&accf[0], S);
    atomicAdd(&accf[1], C);
  }
}

// ---------------- K3: Gram + neg-exp-sum + positive-sim capture ----------------
// grid 512: it = bid>>3 (128-row i-tile), chunk = bid&7 (1024-col j-range)
__global__ __launch_bounds__(256, 2)
void k_gram(const unsigned short* __restrict__ zn,
            const int* __restrict__ pa, const int* __restrict__ pb,
            float* __restrict__ neg_s, int* __restrict__ posCount,
            float* __restrict__ pos_sims) {
  __shared__ unsigned short Bs[64 * 264];
  const int t = threadIdx.x;
  const int lane = t & 63;
  const int w = t >> 6;
  const int l15 = lane & 15;
  const int lg = lane >> 4;
  const int it = blockIdx.x >> 3;
  const int chunk = blockIdx.x & 7;
  const int ibase = it * 128;
  const int jbase0 = chunk * 1024;

  // A fragments: 2 m-tiles x 8 k-steps, loaded straight from normalized bf16
  bf16x8_t afrag[2][8];
  for (int mt = 0; mt < 2; ++mt) {
    int garow = ibase + w * 32 + mt * 16 + l15;
    const unsigned short* asrc = zn + (size_t)garow * DIM;
    for (int ks = 0; ks < 8; ++ks)
      afrag[mt][ks] = *reinterpret_cast<const bf16x8_t*>(asrc + lg * 8 + ks * 32);
  }

  int prow[8], irow[8];
  for (int mt = 0; mt < 2; ++mt)
    for (int r = 0; r < 4; ++r) {
      int g = ibase + w * 32 + mt * 16 + lg * 4 + r;
      irow[mt * 4 + r] = g;
      prow[mt * 4 + r] = piece_of(pa, pb, g);
    }

  float s[8] = {0.f, 0.f, 0.f, 0.f, 0.f, 0.f, 0.f, 0.f};

  for (int jt = 0; jt < 16; ++jt) {
    int jb = jbase0 + jt * 64;
    __syncthreads();
    // stage 64x256 bf16 tile: pure 16B copy. 2048 16B-chunks; chunk = 8 ushorts.
    for (int i = 0; i < 8; ++i) {
      int f = t + i * 256;        // 0..2047
      int r = f >> 5;             // row 0..63
      int c = f & 31;             // 16B chunk in row (8 ushorts)
      bf16x8_t v = *reinterpret_cast<const bf16x8_t*>(zn + (size_t)(jb + r) * DIM + c * 8);
      *reinterpret_cast<bf16x8_t*>(&Bs[r * 264 + c * 8]) = v;
    }
    __syncthreads();
    for (int ct = 0; ct < 4; ++ct) {
      int jj = jb + ct * 16 + l15;
      int pc = piece_of(pa, pb, jj);
      int brow = ct * 16 + l15;
      f32x4_t acc0 = {0.f, 0.f, 0.f, 0.f};
      f32x4_t acc1 = {0.f, 0.f, 0.f, 0.f};
      for (int ks = 0; ks < 8; ++ks) {
        bf16x8_t bfrag = *reinterpret_cast<const bf16x8_t*>(&Bs[brow * 264 + lg * 8 + ks * 32]);
        acc0 = __builtin_amdgcn_mfma_f32_16x16x32_bf16(afrag[0][ks], bfrag, acc0, 0, 0, 0);
        acc1 = __builtin_amdgcn_mfma_f32_16x16x32_bf16(afrag[1][ks], bfrag, acc1, 0, 0, 0);
      }
      for (int r = 0; r < 4; ++r) {
        float sim0 = acc0[r] * INV_T;
        if (pc != prow[r]) {
          s[r] += __expf(sim0 - SHIFT);
        } else if (jj != irow[r]) {
          int slot = atomicAdd(&posCount[irow[r]], 1);
          if (slot < MAXP) pos_sims[(size_t)irow[r] * MAXP + slot] = sim0;
        }
        float sim1 = acc1[r] * INV_T;
        if (pc != prow[4 + r]) {
          s[4 + r] += __expf(sim1 - SHIFT);
        } else if (jj != irow[4 + r]) {
          int slot = atomicAdd(&posCount[irow[4 + r]], 1);
          if (slot < MAXP) pos_sims[(size_t)irow[4 + r] * MAXP + slot] = sim1;
        }
      }
    }
  }
  for (int q = 0; q < 8; ++q) {
    float v = s[q];
    v += __shfl_xor(v, 1, 64);
    v += __shfl_xor(v, 2, 64);
    v += __shfl_xor(v, 4, 64);
    v += __shfl_xor(v, 8, 64);
    if (l15 == 0) atomicAdd(&neg_s[irow[q]], v);
  }
}

// ---------------- K4: positive-pair terms from captured sims ----------------
__global__ void k_pos2(const int* __restrict__ pa, const int* __restrict__ pb,
                       const int* __restrict__ hist, const float* __restrict__ neg_s,
                       const int* __restrict__ posCount, const float* __restrict__ pos_sims,
                       float* __restrict__ accf) {
  int i = blockIdx.x * 256 + threadIdx.x;  // grid covers NTOT exactly
  float lsum = 0.f, lcnt = 0.f;
  int pi = piece_of(pa, pb, i);
  int cnt = hist[pi];
  if (cnt - 1 > 0 && NTOT - cnt > 0) {
    float nlse = SHIFT + logf(neg_s[i]);
    int m = posCount[i];
    if (m > MAXP) m = MAXP;
    for (int s = 0; s < m; ++s) {
      float sim = pos_sims[(size_t)i * MAXP + s];
      float x = nlse - sim;
      lsum += fmaxf(x, 0.f) + log1pf(__expf(-fabsf(x)));
    }
    lcnt = (float)(cnt - 1);
  }
  for (int o = 32; o; o >>= 1) { lsum += __shfl_xor(lsum, o, 64); lcnt += __shfl_xor(lcnt, o, 64); }
  int lane = threadIdx.x & 63;
  if (lane == 0) {
    atomicAdd(&accf[2], lsum);
    atomicAdd(&accf[3], lcnt);
  }
}

// ---------------- K5: finalize ----------------
__global__ void k_final(const float* __restrict__ accf, float* __restrict__ out) {
  float rs = accf[0], rc = accf[1], ps = accf[2], pc = accf[3];
  float l_rank = rc > 0.f ? rs / rc : 0.f;
  float l_con = pc > 0.f ? ps / pc : 0.f;
  out[0] = l_rank + 0.3f * l_con;
  out[1] = l_rank;
  out[2] = l_con;
}

extern "C" void kernel_launch(void* const* d_in, const int* in_sizes, int n_in,
                              void* d_out, int out_size, void* d_ws, size_t ws_size,
                              hipStream_t stream) {
  const float* za     = (const float*)d_in[0];
  const float* zb     = (const float*)d_in[1];
  const float* logits = (const float*)d_in[2];
  const float* la     = (const float*)d_in[3];
  const float* lb     = (const float*)d_in[4];
  const int*   pa     = (const int*)d_in[5];
  const int*   pb     = (const int*)d_in[6];
  float* out = (float*)d_out;

  // ws layout (floats):
  //   [0..4)                accf: rank_sum, rank_cnt, pos_sum, pos_cnt
  //   [4 .. 4+8192)         neg_s
  //   next 1024 (int)       hist
  //   next 8192 (int)       posCount
  //   next 8192*MAXP        pos_sims
  //   next 8192*256 bf16    zn (normalized embeddings)
  float* wsf = (float*)d_ws;
  int*   wsi = (int*)d_ws;
  float* neg_s    = wsf + 4;
  int*   hist     = wsi + 4 + NTOT;
  int*   posCount = wsi + 4 + NTOT + 1024;
  float* pos_sims = wsf + 4 + NTOT + 1024 + NTOT;
  unsigned short* zn = (unsigned short*)(wsf + 4 + NTOT + 1024 + NTOT + (size_t)NTOT * MAXP);

  hipMemsetAsync(d_ws, 0, (size_t)(4 + NTOT + 1024 + NTOT) * 4, stream);
  k_norm<<<NTOT / 4, 256, 0, stream>>>(za, zb, pa, pb, zn, hist);
  k_rank<<<RANK_N / 256, 256, 0, stream>>>(logits, la, lb, wsf);
  k_gram<<<512, 256, 0, stream>>>(zn, pa, pb, neg_s, posCount, pos_sims);
  k_pos2<<<NTOT / 256, 256, 0, stream>>>(pa, pb, hist, neg_s, posCount, pos_sims, wsf);
  k_final<<<1, 1, 0, stream>>>(wsf, out);
}